// Round 1
// baseline (919.558 us; speedup 1.0000x reference)
//
#include <hip/hip_runtime.h>

typedef unsigned short u16;
typedef unsigned int u32;
typedef __attribute__((ext_vector_type(8))) short bf16x8;
typedef __attribute__((ext_vector_type(4))) float f32x4;

__device__ __forceinline__ u16 f2bf(float f) {
  u32 u = __float_as_uint(f);
  u += 0x7fffu + ((u >> 16) & 1u);
  return (u16)(u >> 16);
}

// ---------------- convert x: f32 -> bf16 (straight) ----------------
__global__ __launch_bounds__(256) void k_cvt(const float* __restrict__ in, u16* __restrict__ out, int n) {
  int idx = (blockIdx.x * 256 + threadIdx.x) * 8;
  if (idx >= n) return;
  float4 a = *(const float4*)&in[idx];
  float4 b = *(const float4*)&in[idx + 4];
  union { u16 h[8]; uint4 v; } t;
  t.h[0] = f2bf(a.x); t.h[1] = f2bf(a.y); t.h[2] = f2bf(a.z); t.h[3] = f2bf(a.w);
  t.h[4] = f2bf(b.x); t.h[5] = f2bf(b.y); t.h[6] = f2bf(b.z); t.h[7] = f2bf(b.w);
  *(uint4*)&out[idx] = t.v;
}

// ---------------- transpose+convert: out[c][r] = bf16(in[r][c]); R,C multiples of 64 ----------------
__global__ __launch_bounds__(256) void k_tcvt(const float* __restrict__ in, u16* __restrict__ out, int R, int C) {
  __shared__ u16 T[64 * 72];
  int t = threadIdx.x;
  int r0 = blockIdx.y * 64, c0 = blockIdx.x * 64;
  for (int i = 0; i < 4; i++) {
    int cc = i * 256 + t; int r = cc >> 4; int s = cc & 15;
    float4 v = *(const float4*)&in[(size_t)(r0 + r) * C + c0 + s * 4];
    T[r * 72 + s * 4 + 0] = f2bf(v.x);
    T[r * 72 + s * 4 + 1] = f2bf(v.y);
    T[r * 72 + s * 4 + 2] = f2bf(v.z);
    T[r * 72 + s * 4 + 3] = f2bf(v.w);
  }
  __syncthreads();
  for (int i = 0; i < 2; i++) {
    int cc = i * 256 + t; int c = cc >> 3; int s2 = cc & 7;
    union { u16 h[8]; uint4 v; } tmp;
    for (int e = 0; e < 8; e++) tmp.h[e] = T[(s2 * 8 + e) * 72 + c];
    *(uint4*)&out[(size_t)(c0 + c) * R + r0 + s2 * 8] = tmp.v;
  }
}

// ---------------- transpose v-part of qkv (bf16) into Vt[512][8192] ----------------
__global__ __launch_bounds__(256) void k_tv(const u16* __restrict__ qkv, u16* __restrict__ vt) {
  __shared__ u16 T[64 * 72];
  int t = threadIdx.x;
  int r0 = blockIdx.y * 64;   // token rows
  int d0 = blockIdx.x * 64;   // head-dim rows of vt
  for (int i = 0; i < 2; i++) {
    int cc = i * 256 + t; int r = cc >> 3; int s = cc & 7;
    *(uint4*)&T[r * 72 + s * 8] = *(const uint4*)&qkv[(size_t)(r0 + r) * 1536 + 1024 + d0 + s * 8];
  }
  __syncthreads();
  for (int i = 0; i < 2; i++) {
    int cc = i * 256 + t; int d = cc >> 3; int s2 = cc & 7;
    union { u16 h[8]; uint4 v; } tmp;
    for (int e = 0; e < 8; e++) tmp.h[e] = T[(s2 * 8 + e) * 72 + d];
    *(uint4*)&vt[(size_t)(d0 + d) * 8192 + r0 + s2 * 8] = tmp.v;
  }
}

// ---------------- GEMM: C[M,N] = A[M,K] @ Bt[N,K]^T + bias; bf16 in, bf16 or f32 out ----------------
// m97 structure: 128x128 tile, BK=64, global_load_lds(16B), XOR-swizzled LDS slots.
__global__ __launch_bounds__(256) void k_gemm(const u16* __restrict__ A, const u16* __restrict__ Bt,
                                              const float* __restrict__ bias,
                                              u16* __restrict__ Cb, float* __restrict__ Cf,
                                              int M, int N, int K) {
  __shared__ u16 As[128 * 64];
  __shared__ u16 Bs[128 * 64];
  const int t = threadIdx.x;
  const int l = t & 63, w = t >> 6;
  const int l16 = l & 15, g = l >> 4;
  const int m0 = blockIdx.y * 128, n0 = blockIdx.x * 128;
  const int wr = (w >> 1) * 64, wc = (w & 1) * 64;
  f32x4 acc[4][4] = {};
  for (int kk = 0; kk < K; kk += 64) {
    __syncthreads();
#pragma unroll
    for (int i = 0; i < 4; i++) {
      int c = i * 256 + t;
      int r = c >> 3, g2 = c & 7;
      int sg = g2 ^ (r & 7);   // pre-swizzled global source, linear LDS dest (m173 pattern)
      __builtin_amdgcn_global_load_lds(
          (const __attribute__((address_space(1))) u32*)(A + (size_t)(m0 + r) * K + kk + sg * 8),
          (__attribute__((address_space(3))) u32*)&As[c * 8], 16, 0, 0);
      __builtin_amdgcn_global_load_lds(
          (const __attribute__((address_space(1))) u32*)(Bt + (size_t)(n0 + r) * K + kk + sg * 8),
          (__attribute__((address_space(3))) u32*)&Bs[c * 8], 16, 0, 0);
    }
    __syncthreads();
#pragma unroll
    for (int kh = 0; kh < 2; kh++) {
      bf16x8 a[4];
#pragma unroll
      for (int mi = 0; mi < 4; mi++) {
        int row = wr + 16 * mi + l16;
        int s = (kh * 4 + g) ^ (row & 7);
        a[mi] = *(const bf16x8*)&As[row * 64 + s * 8];
      }
#pragma unroll
      for (int ni = 0; ni < 4; ni++) {
        int row = wc + 16 * ni + l16;
        int s = (kh * 4 + g) ^ (row & 7);
        bf16x8 b = *(const bf16x8*)&Bs[row * 64 + s * 8];
#pragma unroll
        for (int mi = 0; mi < 4; mi++)
          acc[mi][ni] = __builtin_amdgcn_mfma_f32_16x16x32_bf16(a[mi], b, acc[mi][ni], 0, 0, 0);
      }
    }
  }
#pragma unroll
  for (int ni = 0; ni < 4; ni++) {
    int col = n0 + wc + 16 * ni + l16;
    float bv = bias[col];
#pragma unroll
    for (int mi = 0; mi < 4; mi++) {
      int row0 = m0 + wr + 16 * mi + 4 * g;
#pragma unroll
      for (int r = 0; r < 4; r++) {
        float v = acc[mi][ni][r] + bv;
        if (Cf) Cf[(size_t)(row0 + r) * N + col] = v;
        else    Cb[(size_t)(row0 + r) * N + col] = f2bf(v);
      }
    }
  }
}

// ---------------- flash attention: causal, D=512, BQ=32, BK=32, 4 waves ----------------
// wave w: S quadrant rows 16*(w>>1), cols 16*(w&1); PV D-slice [128w,128w+128)
__global__ __launch_bounds__(256) void k_flash(const u16* __restrict__ qkv, const u16* __restrict__ vt,
                                               u16* __restrict__ O) {
  __shared__ u16 Ks[32 * 520];    // padded stride (1040B) -> ~2-way banks on b128 frags
  __shared__ u16 Vts[512 * 40];   // V transposed [d][kv], padded
  __shared__ u16 Ps[32 * 40];
  __shared__ float redm[2][32];
  __shared__ float reds[2][32];
  const int t = threadIdx.x;
  const int l = t & 63, w = t >> 6;
  const int l16 = l & 15, g = l >> 4;
  const int qi = blockIdx.x;
  const int q0 = qi * 32;
  const int wrow = (w >> 1) * 16;
  const int wcol = (w & 1) * 16;
  const int town = w >> 1;
  const float scale = 0.044194173824159216f;  // 1/sqrt(512)

  // Q fragments hoisted to registers (64 VGPR): A-frag row = l&15, k = 8*(l>>4)+j
  bf16x8 qa[16];
#pragma unroll
  for (int ks = 0; ks < 16; ks++)
    qa[ks] = *(const bf16x8*)&qkv[(size_t)(q0 + wrow + l16) * 1536 + ks * 32 + g * 8];

  f32x4 acc[2][8] = {};
  float m_st[2][4], l_st[2][4];
#pragma unroll
  for (int tt = 0; tt < 2; tt++)
#pragma unroll
    for (int r = 0; r < 4; r++) { m_st[tt][r] = -3.0e38f; l_st[tt][r] = 0.f; }

  for (int j0 = 0; j0 <= qi; j0++) {
    __syncthreads();  // protect LDS from previous iteration's readers
#pragma unroll
    for (int i = 0; i < 8; i++) {  // stage K tile (32 x 512)
      int cc = i * 256 + t; int r = cc >> 6; int s = cc & 63;
      *(uint4*)&Ks[r * 520 + s * 8] = *(const uint4*)&qkv[(size_t)(j0 * 32 + r) * 1536 + 512 + s * 8];
    }
#pragma unroll
    for (int i = 0; i < 8; i++) {  // stage Vt tile (512 x 32)
      int cc = i * 256 + t; int d = cc >> 2; int s = cc & 3;
      *(uint4*)&Vts[d * 40 + s * 8] = *(const uint4*)&vt[(size_t)d * 8192 + j0 * 32 + s * 8];
    }
    __syncthreads();

    // QK^T: 16x16 quadrant per wave, K=512
    f32x4 S = {0.f, 0.f, 0.f, 0.f};
#pragma unroll
    for (int ks = 0; ks < 16; ks++) {
      bf16x8 b = *(const bf16x8*)&Ks[(wcol + l16) * 520 + ks * 32 + g * 8];
      S = __builtin_amdgcn_mfma_f32_16x16x32_bf16(qa[ks], b, S, 0, 0, 0);
    }
    float sv[4];
#pragma unroll
    for (int r = 0; r < 4; r++) {
      float s = S[r] * scale;
      if (j0 == qi) {
        int col = j0 * 32 + wcol + l16;
        int row = q0 + wrow + 4 * g + r;
        if (col > row) s = -1e10f;
      }
      sv[r] = s;
      float v = s;
#pragma unroll
      for (int off = 1; off < 16; off <<= 1) v = fmaxf(v, __shfl_xor(v, off));
      if (l16 == 0) redm[w & 1][wrow + 4 * g + r] = v;  // partial row max (this col half)
    }
    __syncthreads();

    float sc[2][4];
#pragma unroll
    for (int tt = 0; tt < 2; tt++)
#pragma unroll
      for (int r = 0; r < 4; r++) {
        int row = 16 * tt + 4 * g + r;
        float mx = fmaxf(redm[0][row], redm[1][row]);
        float mnew = fmaxf(m_st[tt][r], mx);
        sc[tt][r] = __expf(m_st[tt][r] - mnew);
        m_st[tt][r] = mnew;
      }
#pragma unroll
    for (int r = 0; r < 4; r++) {
      float p = __expf(sv[r] - m_st[town][r]);
      Ps[(wrow + 4 * g + r) * 40 + wcol + l16] = f2bf(p);
      float v = p;
#pragma unroll
      for (int off = 1; off < 16; off <<= 1) v += __shfl_xor(v, off);
      if (l16 == 0) reds[w & 1][wrow + 4 * g + r] = v;  // partial row sum
    }
#pragma unroll
    for (int tt = 0; tt < 2; tt++) {
#pragma unroll
      for (int c = 0; c < 8; c++)
#pragma unroll
        for (int r = 0; r < 4; r++)
          acc[tt][c][r] *= sc[tt][r];
#pragma unroll
      for (int r = 0; r < 4; r++) l_st[tt][r] *= sc[tt][r];
    }
    __syncthreads();
#pragma unroll
    for (int tt = 0; tt < 2; tt++)
#pragma unroll
      for (int r = 0; r < 4; r++) {
        int row = 16 * tt + 4 * g + r;
        l_st[tt][r] += reds[0][row] + reds[1][row];
      }
    // PV: O[:, 128w:128w+128] += P[32x32] @ V[32x128-slice]
#pragma unroll
    for (int tt = 0; tt < 2; tt++) {
      bf16x8 pa = *(const bf16x8*)&Ps[(16 * tt + l16) * 40 + g * 8];
#pragma unroll
      for (int c = 0; c < 8; c++) {
        bf16x8 vb = *(const bf16x8*)&Vts[(128 * w + 16 * c + l16) * 40 + g * 8];
        acc[tt][c] = __builtin_amdgcn_mfma_f32_16x16x32_bf16(pa, vb, acc[tt][c], 0, 0, 0);
      }
    }
  }
#pragma unroll
  for (int tt = 0; tt < 2; tt++)
#pragma unroll
    for (int c = 0; c < 8; c++)
#pragma unroll
      for (int r = 0; r < 4; r++) {
        int row = q0 + 16 * tt + 4 * g + r;
        int col = 128 * w + 16 * c + l16;
        O[(size_t)row * 512 + col] = f2bf(acc[tt][c][r] / l_st[tt][r]);
      }
}

extern "C" void kernel_launch(void* const* d_in, const int* in_sizes, int n_in,
                              void* d_out, int out_size, void* d_ws, size_t ws_size,
                              hipStream_t stream) {
  const float* x     = (const float*)d_in[0];
  const float* w_qkv = (const float*)d_in[1];
  const float* b_qkv = (const float*)d_in[2];
  const float* w_out = (const float*)d_in[3];
  const float* b_out = (const float*)d_in[4];
  float* out = (float*)d_out;
  char* ws = (char*)d_ws;
  // ws layout (60 MB total)
  u16* xb    = (u16*)(ws);               // [8192][1024] bf16   16.78 MB
  u16* wqkvT = (u16*)(ws + 16777216);    // [1536][1024] bf16    3.15 MB
  u16* woutT = (u16*)(ws + 19922944);    // [1024][512]  bf16    1.05 MB
  u16* qkv   = (u16*)(ws + 20971520);    // [8192][1536] bf16   25.17 MB
  u16* vt    = (u16*)(ws + 46137344);    // [512][8192]  bf16    8.39 MB
  u16* Ob    = (u16*)(ws + 54525952);    // [8192][512]  bf16    8.39 MB

  k_cvt<<<4096, 256, 0, stream>>>(x, xb, 8192 * 1024);
  k_tcvt<<<dim3(24, 16), 256, 0, stream>>>(w_qkv, wqkvT, 1024, 1536);
  k_tcvt<<<dim3(16, 8), 256, 0, stream>>>(w_out, woutT, 512, 1024);
  k_gemm<<<dim3(12, 64), 256, 0, stream>>>(xb, wqkvT, b_qkv, qkv, nullptr, 8192, 1536, 1024);
  k_tv<<<dim3(8, 128), 256, 0, stream>>>(qkv, vt);
  k_flash<<<256, 256, 0, stream>>>(qkv, vt, Ob);
  k_gemm<<<dim3(8, 64), 256, 0, stream>>>(Ob, woutT, b_out, nullptr, out, 8192, 1024, 512);
}